// Round 2
// baseline (199.920 us; speedup 1.0000x reference)
//
#include <hip/hip_runtime.h>
#include <math.h>

// QuanvolutionHybrid: conv2x2/s2 -> reshape(196,4) -> L2 norm ->
// all-pairs cos^2 >= 0.8 -> degree -> concat(784+196) -> linear(10) -> log_softmax
// One block = one batch element. VALU-issue-bound.
// R2: triangle-only pair phase (symmetry), |d|>=sqrt(0.8) compare, int counts,
//     LDS atomic column scatter, waves 2-3 overlap the linear flat-part.

#define NP 196
#define FEAT 980
#define COS_TH 0.894427191f   // sqrt(0.8)

__global__ __launch_bounds__(256) void quanv_kernel(
    const float* __restrict__ x,        // (8192, 784)
    const float* __restrict__ conv_w,   // (4,1,2,2) = 16
    const float* __restrict__ conv_b,   // (4,)
    const float* __restrict__ lin_w,    // (10, 980)
    const float* __restrict__ lin_b,    // (10,)
    float* __restrict__ out)            // (8192, 10)
{
    __shared__ float    s_x[784];
    __shared__ float4   s_nrm[NP];
    __shared__ float    s_flat[784];
    __shared__ unsigned s_deg[NP];
    __shared__ float    s_red[40];
    __shared__ float    s_logits[10];

    const int b = blockIdx.x;
    const int t = threadIdx.x;

    // ---- Phase 1: stage input image (coalesced float4) ----
    if (t < NP) {
        ((float4*)s_x)[t] = ((const float4*)(x + (size_t)b * 784))[t];
    }
    __syncthreads();

    // ---- Phase 2: 2x2/s2 conv -> flat[784] channel-major ----
    if (t < NP) {
        int h = t / 14, w = t - 14 * (t / 14);
        const float* r0 = s_x + (2 * h) * 28 + 2 * w;
        float x00 = r0[0], x01 = r0[1], x10 = r0[28], x11 = r0[29];
        #pragma unroll
        for (int c = 0; c < 4; ++c) {
            float f = conv_b[c]
                    + conv_w[c * 4 + 0] * x00 + conv_w[c * 4 + 1] * x01
                    + conv_w[c * 4 + 2] * x10 + conv_w[c * 4 + 3] * x11;
            s_flat[c * NP + t] = f;
        }
    }
    __syncthreads();

    // ---- Phase 3: rows = 4 consecutive flat elems; normalize; zero deg ----
    if (t < NP) {
        float4 v = ((const float4*)s_flat)[t];
        float n = sqrtf(v.x * v.x + v.y * v.y + v.z * v.z + v.w * v.w);
        float inv = 1.0f / (n + 1e-12f);
        float4 nv; nv.x = v.x * inv; nv.y = v.y * inv; nv.z = v.z * inv; nv.w = v.w * inv;
        s_nrm[t] = nv;
        s_deg[t] = 0u;
    }
    __syncthreads();

    float acc[10];
    #pragma unroll
    for (int k = 0; k < 10; ++k) acc[k] = 0.0f;

    // ---- Phase 4 (split): pair triangle on threads 0-97; linear flat-part
    //      on threads 128-255 (waves 2-3), overlapped ----
    if (t < 98) {
        const int rowA = t, rowB = 195 - t;
        float4 va = s_nrm[rowA];
        float4 vb = s_nrm[rowB];
        unsigned cA = 0u, cB = 0u;
        for (int q = rowA + 1; q < NP; ++q) {
            float4 o = s_nrm[q];
            float d = va.x * o.x + va.y * o.y + va.z * o.z + va.w * o.w;
            bool hit = fabsf(d) >= COS_TH;
            cA += (unsigned)hit;
            if (hit) atomicAdd(&s_deg[q], 1u);
        }
        for (int q = rowB + 1; q < NP; ++q) {
            float4 o = s_nrm[q];
            float d = vb.x * o.x + vb.y * o.y + vb.z * o.z + vb.w * o.w;
            bool hit = fabsf(d) >= COS_TH;
            cB += (unsigned)hit;
            if (hit) atomicAdd(&s_deg[q], 1u);
        }
        atomicAdd(&s_deg[rowA], cA);
        atomicAdd(&s_deg[rowB], cB);
    } else if (t >= 128) {
        const int tt = t - 128;
        for (int j = tt; j < 784; j += 128) {
            float f = s_flat[j];
            #pragma unroll
            for (int k = 0; k < 10; ++k)
                acc[k] = fmaf(f, lin_w[k * FEAT + j], acc[k]);
        }
    }
    __syncthreads();

    // ---- Phase 5: deg features straight into the linear partials ----
    if (t < NP) {
        float f = (float)s_deg[t];
        #pragma unroll
        for (int k = 0; k < 10; ++k)
            acc[k] = fmaf(f, lin_w[k * FEAT + 784 + t], acc[k]);
    }

    // ---- Phase 6: block reduction of acc[10] ----
    #pragma unroll
    for (int off = 32; off > 0; off >>= 1) {
        #pragma unroll
        for (int k = 0; k < 10; ++k)
            acc[k] += __shfl_down(acc[k], off, 64);
    }
    int wave = t >> 6, lane = t & 63;
    if (lane == 0) {
        #pragma unroll
        for (int k = 0; k < 10; ++k) s_red[wave * 10 + k] = acc[k];
    }
    __syncthreads();
    if (t < 10) {
        s_logits[t] = lin_b[t] + s_red[t] + s_red[10 + t] + s_red[20 + t] + s_red[30 + t];
    }
    __syncthreads();

    // ---- Phase 7: log_softmax over 10 logits ----
    if (t < 10) {
        float m = -INFINITY;
        #pragma unroll
        for (int j = 0; j < 10; ++j) m = fmaxf(m, s_logits[j]);
        float s = 0.0f;
        #pragma unroll
        for (int j = 0; j < 10; ++j) s += expf(s_logits[j] - m);
        out[(size_t)b * 10 + t] = s_logits[t] - m - logf(s);
    }
}

extern "C" void kernel_launch(void* const* d_in, const int* in_sizes, int n_in,
                              void* d_out, int out_size, void* d_ws, size_t ws_size,
                              hipStream_t stream) {
    const float* x      = (const float*)d_in[0];
    const float* conv_w = (const float*)d_in[1];
    const float* conv_b = (const float*)d_in[2];
    const float* lin_w  = (const float*)d_in[3];
    const float* lin_b  = (const float*)d_in[4];
    float* out = (float*)d_out;
    quanv_kernel<<<dim3(8192), dim3(256), 0, stream>>>(x, conv_w, conv_b, lin_w, lin_b, out);
}

// Round 3
// 155.475 us; speedup vs baseline: 1.2859x; 1.2859x over previous
//
#include <hip/hip_runtime.h>
#include <math.h>

// QuanvolutionHybrid: conv2x2/s2 -> reshape(196,4) -> L2 norm ->
// all-pairs cos^2 >= 0.8 -> degree -> concat(784+196) -> linear(10) -> log_softmax
// One block = one batch element. VALU-issue-bound.
// R3: back to R1 structure (all waves uniform, no atomics) + packed fp32
//     (v_pk_fma_f32) over 4 q's per iter with SoA b128 broadcast LDS reads.

#define NP 196
#define FEAT 980
#define COS_TH 0.894427190999915878f   // sqrt(0.8)

typedef float v2f __attribute__((ext_vector_type(2)));
typedef float v4f __attribute__((ext_vector_type(4)));

__global__ __launch_bounds__(256) void quanv_kernel(
    const float* __restrict__ x,        // (8192, 784)
    const float* __restrict__ conv_w,   // (4,1,2,2) = 16
    const float* __restrict__ conv_b,   // (4,)
    const float* __restrict__ lin_w,    // (10, 980)
    const float* __restrict__ lin_b,    // (10,)
    float* __restrict__ out)            // (8192, 10)
{
    __shared__ __align__(16) float s_x[784];
    __shared__ v4f s_nx[49], s_ny[49], s_nz[49], s_nw[49];  // SoA, 196 rows
    __shared__ __align__(16) float s_feats[FEAT];
    __shared__ float s_red[40];
    __shared__ float s_logits[10];

    const int b = blockIdx.x;
    const int t = threadIdx.x;

    // ---- Phase 1: stage input image (coalesced float4) ----
    if (t < NP) {
        ((float4*)s_x)[t] = ((const float4*)(x + (size_t)b * 784))[t];
    }
    __syncthreads();

    // ---- Phase 2: 2x2/s2 conv -> flat[784] channel-major ----
    if (t < NP) {
        int h = t / 14, w = t - 14 * (t / 14);
        const float* r0 = s_x + (2 * h) * 28 + 2 * w;
        float x00 = r0[0], x01 = r0[1], x10 = r0[28], x11 = r0[29];
        #pragma unroll
        for (int c = 0; c < 4; ++c) {
            float f = conv_b[c]
                    + conv_w[c * 4 + 0] * x00 + conv_w[c * 4 + 1] * x01
                    + conv_w[c * 4 + 2] * x10 + conv_w[c * 4 + 3] * x11;
            s_feats[c * NP + t] = f;
        }
    }
    __syncthreads();

    // ---- Phase 3: rows = 4 consecutive flat elems; normalize -> SoA ----
    float4 nv = make_float4(0.f, 0.f, 0.f, 0.f);
    if (t < NP) {
        float4 v = ((const float4*)s_feats)[t];
        float n = sqrtf(v.x * v.x + v.y * v.y + v.z * v.z + v.w * v.w);
        float inv = 1.0f / (n + 1e-12f);
        nv.x = v.x * inv; nv.y = v.y * inv; nv.z = v.z * inv; nv.w = v.w * inv;
        ((float*)s_nx)[t] = nv.x;
        ((float*)s_ny)[t] = nv.y;
        ((float*)s_nz)[t] = nv.z;
        ((float*)s_nw)[t] = nv.w;
    }
    __syncthreads();

    // ---- Phase 4: row sweep, 4 q's per iter, packed fp32 dots ----
    if (t < NP) {
        v2f mx = { nv.x, nv.x };
        v2f my = { nv.y, nv.y };
        v2f mz = { nv.z, nv.z };
        v2f mw = { nv.w, nv.w };
        unsigned cnt = 0u;
        #pragma unroll 7
        for (int j = 0; j < 49; ++j) {
            v4f qx = s_nx[j], qy = s_ny[j], qz = s_nz[j], qw = s_nw[j];
            v2f qx0 = __builtin_shufflevector(qx, qx, 0, 1);
            v2f qx1 = __builtin_shufflevector(qx, qx, 2, 3);
            v2f qy0 = __builtin_shufflevector(qy, qy, 0, 1);
            v2f qy1 = __builtin_shufflevector(qy, qy, 2, 3);
            v2f qz0 = __builtin_shufflevector(qz, qz, 0, 1);
            v2f qz1 = __builtin_shufflevector(qz, qz, 2, 3);
            v2f qw0 = __builtin_shufflevector(qw, qw, 0, 1);
            v2f qw1 = __builtin_shufflevector(qw, qw, 2, 3);
            v2f d0, d1;
            asm("v_pk_mul_f32 %0, %1, %2"     : "=v"(d0) : "v"(qx0), "v"(mx));
            asm("v_pk_mul_f32 %0, %1, %2"     : "=v"(d1) : "v"(qx1), "v"(mx));
            asm("v_pk_fma_f32 %0, %1, %2, %0" : "+v"(d0) : "v"(qy0), "v"(my));
            asm("v_pk_fma_f32 %0, %1, %2, %0" : "+v"(d1) : "v"(qy1), "v"(my));
            asm("v_pk_fma_f32 %0, %1, %2, %0" : "+v"(d0) : "v"(qz0), "v"(mz));
            asm("v_pk_fma_f32 %0, %1, %2, %0" : "+v"(d1) : "v"(qz1), "v"(mz));
            asm("v_pk_fma_f32 %0, %1, %2, %0" : "+v"(d0) : "v"(qw0), "v"(mw));
            asm("v_pk_fma_f32 %0, %1, %2, %0" : "+v"(d1) : "v"(qw1), "v"(mw));
            cnt += (fabsf(d0.x) >= COS_TH);
            cnt += (fabsf(d0.y) >= COS_TH);
            cnt += (fabsf(d1.x) >= COS_TH);
            cnt += (fabsf(d1.y) >= COS_TH);
        }
        s_feats[784 + t] = (float)(cnt - 1u);   // remove self-edge
    }
    __syncthreads();

    // ---- Phase 5: logits[k] = feats . lin_w[k] + lin_b[k] ----
    float acc[10];
    #pragma unroll
    for (int k = 0; k < 10; ++k) acc[k] = 0.0f;
    for (int j = t; j < FEAT; j += 256) {
        float f = s_feats[j];
        #pragma unroll
        for (int k = 0; k < 10; ++k)
            acc[k] = fmaf(f, lin_w[k * FEAT + j], acc[k]);
    }
    #pragma unroll
    for (int off = 32; off > 0; off >>= 1) {
        #pragma unroll
        for (int k = 0; k < 10; ++k)
            acc[k] += __shfl_down(acc[k], off, 64);
    }
    int wave = t >> 6, lane = t & 63;
    if (lane == 0) {
        #pragma unroll
        for (int k = 0; k < 10; ++k) s_red[wave * 10 + k] = acc[k];
    }
    __syncthreads();
    if (t < 10) {
        s_logits[t] = lin_b[t] + s_red[t] + s_red[10 + t] + s_red[20 + t] + s_red[30 + t];
    }
    __syncthreads();

    // ---- Phase 6: log_softmax over 10 logits ----
    if (t < 10) {
        float m = -INFINITY;
        #pragma unroll
        for (int j = 0; j < 10; ++j) m = fmaxf(m, s_logits[j]);
        float s = 0.0f;
        #pragma unroll
        for (int j = 0; j < 10; ++j) s += expf(s_logits[j] - m);
        out[(size_t)b * 10 + t] = s_logits[t] - m - logf(s);
    }
}

extern "C" void kernel_launch(void* const* d_in, const int* in_sizes, int n_in,
                              void* d_out, int out_size, void* d_ws, size_t ws_size,
                              hipStream_t stream) {
    const float* x      = (const float*)d_in[0];
    const float* conv_w = (const float*)d_in[1];
    const float* conv_b = (const float*)d_in[2];
    const float* lin_w  = (const float*)d_in[3];
    const float* lin_b  = (const float*)d_in[4];
    float* out = (float*)d_out;
    quanv_kernel<<<dim3(8192), dim3(256), 0, stream>>>(x, conv_w, conv_b, lin_w, lin_b, out);
}

// Round 4
// 131.449 us; speedup vs baseline: 1.5209x; 1.1828x over previous
//
#include <hip/hip_runtime.h>
#include <math.h>

// QuanvolutionHybrid: conv2x2/s2 -> reshape(196,4) -> L2 norm ->
// all-pairs cos^2 >= 0.8 -> degree -> concat(784+196) -> linear(10) -> log_softmax
// One block = one batch element.
// R4: q-partitioned pair phase (each wave sweeps 52 q's; each lane holds 4 p-rows
//     in registers) -> 208 broadcast b128 reads/block instead of 784. Byte-packed
//     per-subset counts, cross-wave sum via LDS. Linear phase re-mapped to
//     (k, chunk) threads -> no __shfl bpermute storm.

#define NP 196
#define FEAT 980
#define COS_TH 0.894427190999915878f   // sqrt(0.8)

typedef float v2f __attribute__((ext_vector_type(2)));
typedef float v4f __attribute__((ext_vector_type(4)));

__global__ __launch_bounds__(256) void quanv_kernel(
    const float* __restrict__ x,        // (8192, 784)
    const float* __restrict__ conv_w,   // (4,1,2,2) = 16
    const float* __restrict__ conv_b,   // (4,)
    const float* __restrict__ lin_w,    // (10, 980)
    const float* __restrict__ lin_b,    // (10,)
    float* __restrict__ out)            // (8192, 10)
{
    __shared__ __align__(16) float s_x[784];
    __shared__ __align__(16) float4 s_nrmA[256];            // AoS rows, zero-padded
    __shared__ __align__(16) float s_nx[208], s_ny[208], s_nz[208], s_nw[208]; // SoA
    __shared__ __align__(16) float s_feats[FEAT];
    __shared__ unsigned s_cnt[256];
    __shared__ float s_part[256];
    __shared__ float s_logits[10];

    const int b = blockIdx.x;
    const int t = threadIdx.x;
    const int w = t >> 6, l = t & 63;

    // ---- Phase 1: stage input image (coalesced float4) ----
    if (t < NP) {
        ((float4*)s_x)[t] = ((const float4*)(x + (size_t)b * 784))[t];
    }
    __syncthreads();

    // ---- Phase 2: 2x2/s2 conv -> flat[784] channel-major ----
    if (t < NP) {
        int h = t / 14, ww = t - 14 * (t / 14);
        const float* r0 = s_x + (2 * h) * 28 + 2 * ww;
        float x00 = r0[0], x01 = r0[1], x10 = r0[28], x11 = r0[29];
        #pragma unroll
        for (int c = 0; c < 4; ++c) {
            float f = conv_b[c]
                    + conv_w[c * 4 + 0] * x00 + conv_w[c * 4 + 1] * x01
                    + conv_w[c * 4 + 2] * x10 + conv_w[c * 4 + 3] * x11;
            s_feats[c * NP + t] = f;
        }
    }
    __syncthreads();

    // ---- Phase 3: normalize rows -> AoS (padded to 256) + SoA (padded to 208) ----
    if (t < NP) {
        float4 v = ((const float4*)s_feats)[t];
        float n = sqrtf(v.x * v.x + v.y * v.y + v.z * v.z + v.w * v.w);
        float inv = 1.0f / (n + 1e-12f);
        float4 nv; nv.x = v.x * inv; nv.y = v.y * inv; nv.z = v.z * inv; nv.w = v.w * inv;
        s_nrmA[t] = nv;
        s_nx[t] = nv.x; s_ny[t] = nv.y; s_nz[t] = nv.z; s_nw[t] = nv.w;
    } else {
        s_nrmA[t] = make_float4(0.f, 0.f, 0.f, 0.f);
        if (t < 208) { s_nx[t] = 0.f; s_ny[t] = 0.f; s_nz[t] = 0.f; s_nw[t] = 0.f; }
    }
    __syncthreads();

    // ---- Phase 4: pair counts. Lane holds p-rows {l, l+64, l+128, l+192};
    //      wave w sweeps q in [52w, 52w+52) (13 SoA chunks). ----
    {
        float4 p[4];
        #pragma unroll
        for (int r = 0; r < 4; ++r) p[r] = s_nrmA[l + 64 * r];
        v2f mx[4], my[4], mz[4], mw[4];
        #pragma unroll
        for (int r = 0; r < 4; ++r) {
            mx[r] = (v2f){p[r].x, p[r].x};
            my[r] = (v2f){p[r].y, p[r].y};
            mz[r] = (v2f){p[r].z, p[r].z};
            mw[r] = (v2f){p[r].w, p[r].w};
        }
        unsigned cnt0 = 0, cnt1 = 0, cnt2 = 0, cnt3 = 0;
        const v4f* SNX = (const v4f*)s_nx;
        const v4f* SNY = (const v4f*)s_ny;
        const v4f* SNZ = (const v4f*)s_nz;
        const v4f* SNW = (const v4f*)s_nw;
        #pragma unroll 2
        for (int j = 0; j < 13; ++j) {
            int ch = 13 * w + j;
            v4f qx = SNX[ch], qy = SNY[ch], qz = SNZ[ch], qw = SNW[ch];
            v2f qx0 = __builtin_shufflevector(qx, qx, 0, 1);
            v2f qx1 = __builtin_shufflevector(qx, qx, 2, 3);
            v2f qy0 = __builtin_shufflevector(qy, qy, 0, 1);
            v2f qy1 = __builtin_shufflevector(qy, qy, 2, 3);
            v2f qz0 = __builtin_shufflevector(qz, qz, 0, 1);
            v2f qz1 = __builtin_shufflevector(qz, qz, 2, 3);
            v2f qw0 = __builtin_shufflevector(qw, qw, 0, 1);
            v2f qw1 = __builtin_shufflevector(qw, qw, 2, 3);
            unsigned* cp[4] = {&cnt0, &cnt1, &cnt2, &cnt3};
            #pragma unroll
            for (int r = 0; r < 4; ++r) {
                v2f d0, d1;
                asm("v_pk_mul_f32 %0, %1, %2"     : "=v"(d0) : "v"(qx0), "v"(mx[r]));
                asm("v_pk_mul_f32 %0, %1, %2"     : "=v"(d1) : "v"(qx1), "v"(mx[r]));
                asm("v_pk_fma_f32 %0, %1, %2, %0" : "+v"(d0) : "v"(qy0), "v"(my[r]));
                asm("v_pk_fma_f32 %0, %1, %2, %0" : "+v"(d1) : "v"(qy1), "v"(my[r]));
                asm("v_pk_fma_f32 %0, %1, %2, %0" : "+v"(d0) : "v"(qz0), "v"(mz[r]));
                asm("v_pk_fma_f32 %0, %1, %2, %0" : "+v"(d1) : "v"(qz1), "v"(mz[r]));
                asm("v_pk_fma_f32 %0, %1, %2, %0" : "+v"(d0) : "v"(qw0), "v"(mw[r]));
                asm("v_pk_fma_f32 %0, %1, %2, %0" : "+v"(d1) : "v"(qw1), "v"(mw[r]));
                unsigned c = (fabsf(d0.x) >= COS_TH) + (fabsf(d0.y) >= COS_TH)
                           + (fabsf(d1.x) >= COS_TH) + (fabsf(d1.y) >= COS_TH);
                *cp[r] += c;
            }
        }
        s_cnt[t] = cnt0 | (cnt1 << 8) | (cnt2 << 16) | (cnt3 << 24);
    }
    __syncthreads();

    // ---- Phase 5: cross-wave count sum -> degree feature ----
    if (t < NP) {
        int c = t >> 6, ll = t & 63;
        unsigned s = ((s_cnt[ll]       >> (8 * c)) & 255u)
                   + ((s_cnt[64 + ll]  >> (8 * c)) & 255u)
                   + ((s_cnt[128 + ll] >> (8 * c)) & 255u)
                   + ((s_cnt[192 + ll] >> (8 * c)) & 255u);
        s_feats[784 + t] = (float)(s - 1u);   // remove self-edge
    }
    __syncthreads();

    // ---- Phase 6: linear. t<250 -> (k=t/25, c=t%25), float4 dot over 980 ----
    if (t < 250) {
        int k = t / 25, c = t - 25 * (t / 25);
        const float4* wrow = (const float4*)(lin_w + k * FEAT);
        const float4* frow = (const float4*)s_feats;
        float acc = 0.0f;
        for (int i = c; i < 245; i += 25) {
            float4 f = frow[i];
            float4 wv = wrow[i];
            acc = fmaf(f.x, wv.x, acc);
            acc = fmaf(f.y, wv.y, acc);
            acc = fmaf(f.z, wv.z, acc);
            acc = fmaf(f.w, wv.w, acc);
        }
        s_part[t] = acc;
    }
    __syncthreads();

    if (t < 10) {
        float s = lin_b[t];
        #pragma unroll
        for (int i = 0; i < 25; ++i) s += s_part[t * 25 + i];
        s_logits[t] = s;
    }
    __syncthreads();

    // ---- Phase 7: log_softmax over 10 logits ----
    if (t < 10) {
        float m = -INFINITY;
        #pragma unroll
        for (int j = 0; j < 10; ++j) m = fmaxf(m, s_logits[j]);
        float s = 0.0f;
        #pragma unroll
        for (int j = 0; j < 10; ++j) s += expf(s_logits[j] - m);
        out[(size_t)b * 10 + t] = s_logits[t] - m - logf(s);
    }
}

extern "C" void kernel_launch(void* const* d_in, const int* in_sizes, int n_in,
                              void* d_out, int out_size, void* d_ws, size_t ws_size,
                              hipStream_t stream) {
    const float* x      = (const float*)d_in[0];
    const float* conv_w = (const float*)d_in[1];
    const float* conv_b = (const float*)d_in[2];
    const float* lin_w  = (const float*)d_in[3];
    const float* lin_b  = (const float*)d_in[4];
    float* out = (float*)d_out;
    quanv_kernel<<<dim3(8192), dim3(256), 0, stream>>>(x, conv_w, conv_b, lin_w, lin_b, out);
}

// Round 5
// 130.830 us; speedup vs baseline: 1.5281x; 1.0047x over previous
//
#include <hip/hip_runtime.h>
#include <math.h>

// QuanvolutionHybrid: conv2x2/s2 -> reshape(196,4) -> L2 norm ->
// all-pairs cos^2 >= 0.8 -> degree -> concat(784+196) -> linear(10) -> log_softmax
// One block = one batch element. VALU-issue-bound.
// R5: R4 structure + __launch_bounds__(256,5) so the 16 loop-invariant v2f
//     broadcast pairs stay in VGPRs (R4's 36-VGPR cap forced in-loop
//     rematerialization ~ +35% phase-4 issue). s_nrmA dropped (SoA scalar
//     loads, stride-1 = conflict-free). cnt as plain unrolled array.

#define NP 196
#define FEAT 980
#define COS_TH 0.894427190999915878f   // sqrt(0.8)

typedef float v2f __attribute__((ext_vector_type(2)));
typedef float v4f __attribute__((ext_vector_type(4)));

__global__ __launch_bounds__(256, 5) void quanv_kernel(
    const float* __restrict__ x,        // (8192, 784)
    const float* __restrict__ conv_w,   // (4,1,2,2) = 16
    const float* __restrict__ conv_b,   // (4,)
    const float* __restrict__ lin_w,    // (10, 980)
    const float* __restrict__ lin_b,    // (10,)
    float* __restrict__ out)            // (8192, 10)
{
    __shared__ __align__(16) float s_x[784];
    __shared__ __align__(16) float s_nx[256], s_ny[256], s_nz[256], s_nw[256]; // SoA, zero-padded
    __shared__ __align__(16) float s_feats[FEAT];
    __shared__ unsigned s_cnt[256];
    __shared__ float s_part[256];
    __shared__ float s_logits[10];

    const int b = blockIdx.x;
    const int t = threadIdx.x;
    const int w = t >> 6, l = t & 63;

    // ---- Phase 1: stage input image (coalesced float4) ----
    if (t < NP) {
        ((float4*)s_x)[t] = ((const float4*)(x + (size_t)b * 784))[t];
    }
    __syncthreads();

    // ---- Phase 2: 2x2/s2 conv -> flat[784] channel-major ----
    if (t < NP) {
        int h = t / 14, ww = t - 14 * (t / 14);
        const float* r0 = s_x + (2 * h) * 28 + 2 * ww;
        float x00 = r0[0], x01 = r0[1], x10 = r0[28], x11 = r0[29];
        #pragma unroll
        for (int c = 0; c < 4; ++c) {
            float f = conv_b[c]
                    + conv_w[c * 4 + 0] * x00 + conv_w[c * 4 + 1] * x01
                    + conv_w[c * 4 + 2] * x10 + conv_w[c * 4 + 3] * x11;
            s_feats[c * NP + t] = f;
        }
    }
    __syncthreads();

    // ---- Phase 3: normalize rows -> SoA (zero-padded to 256) ----
    if (t < NP) {
        float4 v = ((const float4*)s_feats)[t];
        float n = sqrtf(v.x * v.x + v.y * v.y + v.z * v.z + v.w * v.w);
        float inv = 1.0f / (n + 1e-12f);
        s_nx[t] = v.x * inv; s_ny[t] = v.y * inv;
        s_nz[t] = v.z * inv; s_nw[t] = v.w * inv;
    } else {
        s_nx[t] = 0.f; s_ny[t] = 0.f; s_nz[t] = 0.f; s_nw[t] = 0.f;
    }
    __syncthreads();

    // ---- Phase 4: pair counts. Lane holds p-rows {l, l+64, l+128, l+192};
    //      wave w sweeps q in [52w, 52w+52) (13 SoA float4 chunks). ----
    {
        v2f mx[4], my[4], mz[4], mw[4];
        #pragma unroll
        for (int r = 0; r < 4; ++r) {
            int row = l + 64 * r;
            float px = s_nx[row], py = s_ny[row], pz = s_nz[row], pw = s_nw[row];
            mx[r] = (v2f){px, px};
            my[r] = (v2f){py, py};
            mz[r] = (v2f){pz, pz};
            mw[r] = (v2f){pw, pw};
        }
        unsigned cnt[4] = {0u, 0u, 0u, 0u};
        const v4f* SNX = (const v4f*)s_nx;
        const v4f* SNY = (const v4f*)s_ny;
        const v4f* SNZ = (const v4f*)s_nz;
        const v4f* SNW = (const v4f*)s_nw;
        #pragma unroll 2
        for (int j = 0; j < 13; ++j) {
            int ch = 13 * w + j;
            v4f qx = SNX[ch], qy = SNY[ch], qz = SNZ[ch], qw = SNW[ch];
            v2f qx0 = __builtin_shufflevector(qx, qx, 0, 1);
            v2f qx1 = __builtin_shufflevector(qx, qx, 2, 3);
            v2f qy0 = __builtin_shufflevector(qy, qy, 0, 1);
            v2f qy1 = __builtin_shufflevector(qy, qy, 2, 3);
            v2f qz0 = __builtin_shufflevector(qz, qz, 0, 1);
            v2f qz1 = __builtin_shufflevector(qz, qz, 2, 3);
            v2f qw0 = __builtin_shufflevector(qw, qw, 0, 1);
            v2f qw1 = __builtin_shufflevector(qw, qw, 2, 3);
            #pragma unroll
            for (int r = 0; r < 4; ++r) {
                v2f d0, d1;
                asm("v_pk_mul_f32 %0, %1, %2"     : "=v"(d0) : "v"(qx0), "v"(mx[r]));
                asm("v_pk_mul_f32 %0, %1, %2"     : "=v"(d1) : "v"(qx1), "v"(mx[r]));
                asm("v_pk_fma_f32 %0, %1, %2, %0" : "+v"(d0) : "v"(qy0), "v"(my[r]));
                asm("v_pk_fma_f32 %0, %1, %2, %0" : "+v"(d1) : "v"(qy1), "v"(my[r]));
                asm("v_pk_fma_f32 %0, %1, %2, %0" : "+v"(d0) : "v"(qz0), "v"(mz[r]));
                asm("v_pk_fma_f32 %0, %1, %2, %0" : "+v"(d1) : "v"(qz1), "v"(mz[r]));
                asm("v_pk_fma_f32 %0, %1, %2, %0" : "+v"(d0) : "v"(qw0), "v"(mw[r]));
                asm("v_pk_fma_f32 %0, %1, %2, %0" : "+v"(d1) : "v"(qw1), "v"(mw[r]));
                cnt[r] += (fabsf(d0.x) >= COS_TH);
                cnt[r] += (fabsf(d0.y) >= COS_TH);
                cnt[r] += (fabsf(d1.x) >= COS_TH);
                cnt[r] += (fabsf(d1.y) >= COS_TH);
            }
        }
        s_cnt[t] = cnt[0] | (cnt[1] << 8) | (cnt[2] << 16) | (cnt[3] << 24);
    }
    __syncthreads();

    // ---- Phase 5: cross-wave count sum -> degree feature ----
    if (t < NP) {
        int c = t >> 6, ll = t & 63;
        unsigned s = ((s_cnt[ll]       >> (8 * c)) & 255u)
                   + ((s_cnt[64 + ll]  >> (8 * c)) & 255u)
                   + ((s_cnt[128 + ll] >> (8 * c)) & 255u)
                   + ((s_cnt[192 + ll] >> (8 * c)) & 255u);
        s_feats[784 + t] = (float)(s - 1u);   // remove self-edge
    }
    __syncthreads();

    // ---- Phase 6: linear. t<250 -> (k=t/25, c=t%25), float4 dot over 980 ----
    if (t < 250) {
        int k = t / 25, c = t - 25 * (t / 25);
        const float4* wrow = (const float4*)(lin_w + k * FEAT);
        const float4* frow = (const float4*)s_feats;
        float acc = 0.0f;
        for (int i = c; i < 245; i += 25) {
            float4 f = frow[i];
            float4 wv = wrow[i];
            acc = fmaf(f.x, wv.x, acc);
            acc = fmaf(f.y, wv.y, acc);
            acc = fmaf(f.z, wv.z, acc);
            acc = fmaf(f.w, wv.w, acc);
        }
        s_part[t] = acc;
    }
    __syncthreads();

    if (t < 10) {
        float s = lin_b[t];
        #pragma unroll
        for (int i = 0; i < 25; ++i) s += s_part[t * 25 + i];
        s_logits[t] = s;
    }
    __syncthreads();

    // ---- Phase 7: log_softmax over 10 logits ----
    if (t < 10) {
        float m = -INFINITY;
        #pragma unroll
        for (int j = 0; j < 10; ++j) m = fmaxf(m, s_logits[j]);
        float s = 0.0f;
        #pragma unroll
        for (int j = 0; j < 10; ++j) s += expf(s_logits[j] - m);
        out[(size_t)b * 10 + t] = s_logits[t] - m - logf(s);
    }
}

extern "C" void kernel_launch(void* const* d_in, const int* in_sizes, int n_in,
                              void* d_out, int out_size, void* d_ws, size_t ws_size,
                              hipStream_t stream) {
    const float* x      = (const float*)d_in[0];
    const float* conv_w = (const float*)d_in[1];
    const float* conv_b = (const float*)d_in[2];
    const float* lin_w  = (const float*)d_in[3];
    const float* lin_b  = (const float*)d_in[4];
    float* out = (float*)d_out;
    quanv_kernel<<<dim3(8192), dim3(256), 0, stream>>>(x, conv_w, conv_b, lin_w, lin_b, out);
}

// Round 6
// 121.482 us; speedup vs baseline: 1.6457x; 1.0769x over previous
//
#include <hip/hip_runtime.h>
#include <math.h>

// QuanvolutionHybrid: conv2x2/s2 -> reshape(196,4) -> L2 norm ->
// all-pairs cos^2 >= 0.8 -> degree -> concat(784+196) -> linear(10) -> log_softmax
// One block = one batch element. VALU-issue-bound.
// R6: (a) opaque-asm pin of the 12 {p,p} broadcast pairs so LLVM can't
//     rematerialize them in-loop (R5: VGPR=36 proved remat, ~400 movs/wave);
//     (b) main pair loop covers rows 0-191 only (3 rows/lane, zero dead-lane
//     waste); rows 192-195 via ballot/popcount tail (~45 insts vs ~208).

#define NP 196
#define FEAT 980
#define COS_TH 0.894427190999915878f   // sqrt(0.8)

typedef float v2f __attribute__((ext_vector_type(2)));
typedef float v4f __attribute__((ext_vector_type(4)));

__global__ __launch_bounds__(256, 5) void quanv_kernel(
    const float* __restrict__ x,        // (8192, 784)
    const float* __restrict__ conv_w,   // (4,1,2,2) = 16
    const float* __restrict__ conv_b,   // (4,)
    const float* __restrict__ lin_w,    // (10, 980)
    const float* __restrict__ lin_b,    // (10,)
    float* __restrict__ out)            // (8192, 10)
{
    __shared__ __align__(16) float s_x[784];
    __shared__ __align__(16) float s_nx[256], s_ny[256], s_nz[256], s_nw[256]; // SoA, zero-padded
    __shared__ __align__(16) float s_feats[FEAT];
    __shared__ unsigned s_cnt[256];
    __shared__ float s_part[256];
    __shared__ float s_logits[10];

    const int b = blockIdx.x;
    const int t = threadIdx.x;
    const int w = t >> 6, l = t & 63;

    // ---- Phase 1: stage input image (coalesced float4) ----
    if (t < NP) {
        ((float4*)s_x)[t] = ((const float4*)(x + (size_t)b * 784))[t];
    }
    __syncthreads();

    // ---- Phase 2: 2x2/s2 conv -> flat[784] channel-major ----
    if (t < NP) {
        int h = t / 14, ww = t - 14 * (t / 14);
        const float* r0 = s_x + (2 * h) * 28 + 2 * ww;
        float x00 = r0[0], x01 = r0[1], x10 = r0[28], x11 = r0[29];
        #pragma unroll
        for (int c = 0; c < 4; ++c) {
            float f = conv_b[c]
                    + conv_w[c * 4 + 0] * x00 + conv_w[c * 4 + 1] * x01
                    + conv_w[c * 4 + 2] * x10 + conv_w[c * 4 + 3] * x11;
            s_feats[c * NP + t] = f;
        }
    }
    __syncthreads();

    // ---- Phase 3: normalize rows -> SoA (zero-padded to 256) ----
    if (t < NP) {
        float4 v = ((const float4*)s_feats)[t];
        float n = sqrtf(v.x * v.x + v.y * v.y + v.z * v.z + v.w * v.w);
        float inv = 1.0f / (n + 1e-12f);
        s_nx[t] = v.x * inv; s_ny[t] = v.y * inv;
        s_nz[t] = v.z * inv; s_nw[t] = v.w * inv;
    } else {
        s_nx[t] = 0.f; s_ny[t] = 0.f; s_nz[t] = 0.f; s_nw[t] = 0.f;
    }
    __syncthreads();

    // ---- Phase 4a: pair counts, rows {l, l+64, l+128} (all real);
    //      wave w sweeps q in [52w, 52w+52) (13 SoA float4 chunks). ----
    {
        v2f mx[3], my[3], mz[3], mw[3];
        #pragma unroll
        for (int r = 0; r < 3; ++r) {
            int row = l + 64 * r;
            float px = s_nx[row], py = s_ny[row], pz = s_nz[row], pw = s_nw[row];
            mx[r] = (v2f){px, px};
            my[r] = (v2f){py, py};
            mz[r] = (v2f){pz, pz};
            mw[r] = (v2f){pw, pw};
        }
        // Opaque pin: uses below reference the asm result -> no rematerialization.
        #pragma unroll
        for (int r = 0; r < 3; ++r)
            asm("" : "+v"(mx[r]), "+v"(my[r]), "+v"(mz[r]), "+v"(mw[r]));

        unsigned cnt[3] = {0u, 0u, 0u};
        const v4f* SNX = (const v4f*)s_nx;
        const v4f* SNY = (const v4f*)s_ny;
        const v4f* SNZ = (const v4f*)s_nz;
        const v4f* SNW = (const v4f*)s_nw;
        #pragma unroll 2
        for (int j = 0; j < 13; ++j) {
            int ch = 13 * w + j;
            v4f qx = SNX[ch], qy = SNY[ch], qz = SNZ[ch], qw = SNW[ch];
            v2f qx0 = __builtin_shufflevector(qx, qx, 0, 1);
            v2f qx1 = __builtin_shufflevector(qx, qx, 2, 3);
            v2f qy0 = __builtin_shufflevector(qy, qy, 0, 1);
            v2f qy1 = __builtin_shufflevector(qy, qy, 2, 3);
            v2f qz0 = __builtin_shufflevector(qz, qz, 0, 1);
            v2f qz1 = __builtin_shufflevector(qz, qz, 2, 3);
            v2f qw0 = __builtin_shufflevector(qw, qw, 0, 1);
            v2f qw1 = __builtin_shufflevector(qw, qw, 2, 3);
            #pragma unroll
            for (int r = 0; r < 3; ++r) {
                v2f d0, d1;
                asm("v_pk_mul_f32 %0, %1, %2"     : "=v"(d0) : "v"(qx0), "v"(mx[r]));
                asm("v_pk_mul_f32 %0, %1, %2"     : "=v"(d1) : "v"(qx1), "v"(mx[r]));
                asm("v_pk_fma_f32 %0, %1, %2, %0" : "+v"(d0) : "v"(qy0), "v"(my[r]));
                asm("v_pk_fma_f32 %0, %1, %2, %0" : "+v"(d1) : "v"(qy1), "v"(my[r]));
                asm("v_pk_fma_f32 %0, %1, %2, %0" : "+v"(d0) : "v"(qz0), "v"(mz[r]));
                asm("v_pk_fma_f32 %0, %1, %2, %0" : "+v"(d1) : "v"(qz1), "v"(mz[r]));
                asm("v_pk_fma_f32 %0, %1, %2, %0" : "+v"(d0) : "v"(qw0), "v"(mw[r]));
                asm("v_pk_fma_f32 %0, %1, %2, %0" : "+v"(d1) : "v"(qw1), "v"(mw[r]));
                cnt[r] += (fabsf(d0.x) >= COS_TH);
                cnt[r] += (fabsf(d0.y) >= COS_TH);
                cnt[r] += (fabsf(d1.x) >= COS_TH);
                cnt[r] += (fabsf(d1.y) >= COS_TH);
            }
        }
        s_cnt[t] = cnt[0] | (cnt[1] << 8) | (cnt[2] << 16);
    }

    // ---- Phase 4b: tail rows 192..195, one per wave; lane l covers
    //      q = {l, 64+l, 128+l, 192+l} (zero-pad makes q>=196 a guaranteed miss)
    {
        int row = 192 + w;
        float px = s_nx[row], py = s_ny[row], pz = s_nz[row], pw = s_nw[row];
        unsigned total = 0u;
        #pragma unroll
        for (int j = 0; j < 4; ++j) {
            int q = 64 * j + l;
            float d = px * s_nx[q];
            d = fmaf(py, s_ny[q], d);
            d = fmaf(pz, s_nz[q], d);
            d = fmaf(pw, s_nw[q], d);
            unsigned long long m = __ballot(fabsf(d) >= COS_TH);
            total += (unsigned)__popcll(m);
        }
        if (l == 0) s_feats[784 + row] = (float)(total - 1u);  // self-edge
    }
    __syncthreads();

    // ---- Phase 5: cross-wave count sum -> degree feature (rows 0..191) ----
    if (t < 192) {
        int c = t >> 6, ll = t & 63;
        unsigned s = ((s_cnt[ll]       >> (8 * c)) & 255u)
                   + ((s_cnt[64 + ll]  >> (8 * c)) & 255u)
                   + ((s_cnt[128 + ll] >> (8 * c)) & 255u)
                   + ((s_cnt[192 + ll] >> (8 * c)) & 255u);
        s_feats[784 + t] = (float)(s - 1u);   // remove self-edge
    }
    __syncthreads();

    // ---- Phase 6: linear. t<250 -> (k=t/25, c=t%25), float4 dot over 980 ----
    if (t < 250) {
        int k = t / 25, c = t - 25 * (t / 25);
        const float4* wrow = (const float4*)(lin_w + k * FEAT);
        const float4* frow = (const float4*)s_feats;
        float acc = 0.0f;
        for (int i = c; i < 245; i += 25) {
            float4 f = frow[i];
            float4 wv = wrow[i];
            acc = fmaf(f.x, wv.x, acc);
            acc = fmaf(f.y, wv.y, acc);
            acc = fmaf(f.z, wv.z, acc);
            acc = fmaf(f.w, wv.w, acc);
        }
        s_part[t] = acc;
    }
    __syncthreads();

    if (t < 10) {
        float s = lin_b[t];
        #pragma unroll
        for (int i = 0; i < 25; ++i) s += s_part[t * 25 + i];
        s_logits[t] = s;
    }
    __syncthreads();

    // ---- Phase 7: log_softmax over 10 logits ----
    if (t < 10) {
        float m = -INFINITY;
        #pragma unroll
        for (int j = 0; j < 10; ++j) m = fmaxf(m, s_logits[j]);
        float s = 0.0f;
        #pragma unroll
        for (int j = 0; j < 10; ++j) s += expf(s_logits[j] - m);
        out[(size_t)b * 10 + t] = s_logits[t] - m - logf(s);
    }
}

extern "C" void kernel_launch(void* const* d_in, const int* in_sizes, int n_in,
                              void* d_out, int out_size, void* d_ws, size_t ws_size,
                              hipStream_t stream) {
    const float* x      = (const float*)d_in[0];
    const float* conv_w = (const float*)d_in[1];
    const float* conv_b = (const float*)d_in[2];
    const float* lin_w  = (const float*)d_in[3];
    const float* lin_b  = (const float*)d_in[4];
    float* out = (float*)d_out;
    quanv_kernel<<<dim3(8192), dim3(256), 0, stream>>>(x, conv_w, conv_b, lin_w, lin_b, out);
}